// Round 8
// baseline (85.553 us; speedup 1.0000x reference)
//
#include <hip/hip_runtime.h>
#include <hip/hip_bf16.h>

// NF4 double-quant dequantize + x @ W^T   (MFMA, K-split x2, prefetch, dbuf LDS)
// x: [32][4096] f32 in memory. out: [32][14336] f32 in memory (pinned r5-r7).
// packed: [N/2] int32, one byte per word; even k = low nibble.
// y[r,o] = sum_k x[r,k] * deq(W[o,k]),  deq = nib*cs - offset[b]*cs
// cs = (absmax[b]/code[b]) * (g_absmax[g]/g_code[g]),  b = elem/64, g = elem/256

#define OUT_D 14336
#define IN_D  4096
#define B_D   32
#define KC    256                  // k-chunk per LDS stage
#define OTILE 32                   // W rows per block
#define KSPLIT 2                   // k-range split across blockIdx.y
#define CHUNKS (IN_D / KC / KSPLIT)  // 8 chunks per block
#define LSTRIDE 264                // bf16 elems per LDS row (256 + 8 pad)

typedef __attribute__((ext_vector_type(4))) float f32x4;
typedef __attribute__((ext_vector_type(4))) int   i32x4;
typedef __bf16 bf16x8 __attribute__((ext_vector_type(8)));
using u16 = unsigned short;

__global__ __launch_bounds__(256) void nf4_linear_kernel(
    const float* __restrict__ x,        // [32][4096] f32
    const int*  __restrict__ packed,    // [N/2]
    const float* __restrict__ absmax,   // [NB]
    const float* __restrict__ code,     // [NB]
    const float* __restrict__ offset,   // [NB]
    const float* __restrict__ g_absmax, // [NG]
    const float* __restrict__ g_code,   // [NG]
    float* __restrict__ out)            // [32][14336] f32 (pre-zeroed)
{
    __shared__ u16 wlds[2][OTILE * LSTRIDE];

    const int t      = threadIdx.x;
    const int o_base = blockIdx.x * OTILE;
    const int kz     = blockIdx.y;          // 0..KSPLIT-1
    const int kc0    = kz * CHUNKS;

    // staging roles: 8 threads per W row, 32-elem (16-word) segment each
    const int wrow = t >> 3;        // 0..31
    const int wseg = t & 7;         // 0..7
    const int o    = o_base + wrow;

    // mfma roles: wave -> (m-half, n-half)
    const int wave   = t >> 6;
    const int lane   = t & 63;
    const int m_base = (wave & 1) * 16;
    const int n_base = (wave >> 1) * 16;
    const int frow   = lane & 15;        // own-row index for A/B frags
    const int kk     = (lane >> 4) * 8;  // k sub-offset

    f32x4 acc = {0.f, 0.f, 0.f, 0.f};

    // ---- prefetch chunk 0's packed words into registers ----
    i32x4 pk[4];
    {
        const i32x4* ps = reinterpret_cast<const i32x4*>(
            packed + o * (IN_D / 2) + kc0 * (KC / 2) + wseg * 16);
        #pragma unroll
        for (int j = 0; j < 4; ++j) pk[j] = ps[j];
    }

    int p = 0;
    for (int i = 0; i < CHUNKS; ++i) {
        const int kc = kc0 + i;

        // ---- dequant current regs -> wlds[p] ----
        const int bidx = o * 64 + kc * 4 + (wseg >> 1);
        const int gidx = o * 16 + kc;
        const float cs  = (absmax[bidx] / code[bidx]) * (g_absmax[gidx] / g_code[gidx]);
        const float noc = -offset[bidx] * cs;

        u16* wdst = &wlds[p][wrow * LSTRIDE + wseg * 32];
        #pragma unroll
        for (int j = 0; j < 4; ++j) {
            bf16x8 r;
            #pragma unroll
            for (int wi = 0; wi < 4; ++wi) {
                int w = pk[j][wi];
                float lo = (float)(w & 15);
                float hi = (float)((w >> 4) & 15);
                r[wi * 2]     = (__bf16)fmaf(lo, cs, noc);
                r[wi * 2 + 1] = (__bf16)fmaf(hi, cs, noc);
            }
            *reinterpret_cast<bf16x8*>(wdst + j * 8) = r;
        }
        __syncthreads();

        // ---- issue next chunk's global loads (hidden under MFMA) ----
        if (i + 1 < CHUNKS) {
            const i32x4* ps = reinterpret_cast<const i32x4*>(
                packed + o * (IN_D / 2) + (kc + 1) * (KC / 2) + wseg * 16);
            #pragma unroll
            for (int j = 0; j < 4; ++j) pk[j] = ps[j];
        }

        // ---- MFMA: x fragment direct from global (L2-resident), W from LDS ----
        const float* xbase = x + (m_base + frow) * IN_D + kc * KC + kk;
        const u16*   wp    = &wlds[p][(n_base + frow) * LSTRIDE + kk];
        #pragma unroll
        for (int ks = 0; ks < KC / 32; ++ks) {
            f32x4 xa = *reinterpret_cast<const f32x4*>(xbase + ks * 32);
            f32x4 xb = *reinterpret_cast<const f32x4*>(xbase + ks * 32 + 4);
            bf16x8 a;
            a[0] = (__bf16)xa[0]; a[1] = (__bf16)xa[1];
            a[2] = (__bf16)xa[2]; a[3] = (__bf16)xa[3];
            a[4] = (__bf16)xb[0]; a[5] = (__bf16)xb[1];
            a[6] = (__bf16)xb[2]; a[7] = (__bf16)xb[3];
            bf16x8 b = *reinterpret_cast<const bf16x8*>(wp + ks * 32);
            acc = __builtin_amdgcn_mfma_f32_16x16x32_bf16(a, b, acc, 0, 0, 0);
        }
        p ^= 1;
    }

    // ---- epilogue: D col = lane&15 (out col), row = (lane>>4)*4 + i (batch) ----
    // KSPLIT=2 partial sums: atomicAdd; exactly 2 contributions -> a+b == b+a,
    // bitwise deterministic.
    const int oc = o_base + n_base + frow;
    const int r0 = m_base + (lane >> 4) * 4;
    #pragma unroll
    for (int i = 0; i < 4; ++i) {
        atomicAdd(&out[(r0 + i) * OUT_D + oc], acc[i]);
    }
}

extern "C" void kernel_launch(void* const* d_in, const int* in_sizes, int n_in,
                              void* d_out, int out_size, void* d_ws, size_t ws_size,
                              hipStream_t stream) {
    const void* px = nullptr;
    const void* ppk = nullptr;
    const void* trio[3] = {nullptr, nullptr, nullptr};
    const void* pair[2] = {nullptr, nullptr};
    int ntrio = 0, npair = 0;
    const int SZ_X   = B_D * IN_D;            // 131072
    const int SZ_PK  = OUT_D * (IN_D / 2);    // 29360128
    const int SZ_NB  = OUT_D * (IN_D / 64);   // 917504
    const int SZ_NG  = OUT_D * (IN_D / 256);  // 229376
    for (int i = 0; i < n_in; ++i) {
        int s = in_sizes[i];
        if (s == SZ_X) px = d_in[i];
        else if (s == SZ_PK) ppk = d_in[i];
        else if (s == SZ_NB) { if (ntrio < 3) trio[ntrio++] = d_in[i]; }
        else if (s == SZ_NG) { if (npair < 2) pair[npair++] = d_in[i]; }
    }
    if (!px || !ppk || ntrio != 3 || npair != 2) {
        px = d_in[0]; ppk = d_in[1];
        trio[0] = d_in[2]; trio[1] = d_in[3]; trio[2] = d_in[4];
        pair[0] = d_in[5]; pair[1] = d_in[6];
    }

    // zero-init output (graph-capturable memset node); kernel accumulates
    hipMemsetAsync(d_out, 0, (size_t)out_size * sizeof(float), stream);

    nf4_linear_kernel<<<dim3(OUT_D / OTILE, KSPLIT), dim3(256), 0, stream>>>(
        (const float*)px, (const int*)ppk,
        (const float*)trio[0], (const float*)trio[1], (const float*)trio[2],
        (const float*)pair[0], (const float*)pair[1],
        (float*)d_out);
}

// Round 9
// 42.306 us; speedup vs baseline: 2.0223x; 2.0223x over previous
//
#include <hip/hip_runtime.h>
#include <hip/hip_bf16.h>

// NF4 double-quant dequantize + x @ W^T   (MFMA, dbuf LDS, 1-chunk prefetch)
// x: [32][4096] f32 in memory. out: [32][14336] f32 in memory (pinned r5-r7).
// packed: [N/2] int32, one byte per word; even k = low nibble.
// y[r,o] = sum_k x[r,k] * deq(W[o,k]),  deq = nib*cs - offset[b]*cs
// cs = (absmax[b]/code[b]) * (g_absmax[g]/g_code[g]),  b = elem/64, g = elem/256

#define OUT_D 14336
#define IN_D  4096
#define B_D   32
#define KC    256                 // k-chunk per LDS stage
#define OTILE 32                  // W rows per block
#define CHUNKS (IN_D / KC)        // 16
#define LSTRIDE 264               // bf16 elems per LDS row (256 + 8 pad)

typedef __attribute__((ext_vector_type(4))) float f32x4;
typedef __attribute__((ext_vector_type(4))) int   i32x4;
typedef __bf16 bf16x8 __attribute__((ext_vector_type(8)));
typedef __bf16 bf16x4 __attribute__((ext_vector_type(4)));
using u16 = unsigned short;

__global__ __launch_bounds__(256) void nf4_linear_kernel(
    const float* __restrict__ x,        // [32][4096] f32
    const int*  __restrict__ packed,    // [N/2]
    const float* __restrict__ absmax,   // [NB]
    const float* __restrict__ code,     // [NB]
    const float* __restrict__ offset,   // [NB]
    const float* __restrict__ g_absmax, // [NG]
    const float* __restrict__ g_code,   // [NG]
    float* __restrict__ out)            // [32][14336] f32
{
    __shared__ u16 wlds[2][OTILE * LSTRIDE];
    __shared__ u16 xlds[2][B_D * LSTRIDE];

    const int t      = threadIdx.x;
    const int o_base = blockIdx.x * OTILE;

    // staging roles: 8 threads per W row, 32-elem (16-word) segment each
    const int wrow = t >> 3;        // 0..31
    const int wseg = t & 7;         // 0..7
    const int o    = o_base + wrow;

    // mfma roles: wave -> (m-half, n-half)
    const int wave   = t >> 6;
    const int lane   = t & 63;
    const int m_base = (wave & 1) * 16;
    const int n_base = (wave >> 1) * 16;
    const int frow   = lane & 15;        // own-row index for A/B frags
    const int kk     = (lane >> 4) * 8;  // k sub-offset

    const int* pbase = packed + o * (IN_D / 2) + wseg * 16;

    f32x4 acc = {0.f, 0.f, 0.f, 0.f};

    i32x4 pkA[4], pkB[4];
    f32x4 pxA[8], pxB[8];
    float amA, cdA, ofA, gaA, gcA;
    float amB, cdB, ofB, gaB, gcB;

#define LOADPK(DST, KCI) { \
    const i32x4* ps = reinterpret_cast<const i32x4*>(pbase + (KCI) * (KC / 2)); \
    DST[0] = ps[0]; DST[1] = ps[1]; DST[2] = ps[2]; DST[3] = ps[3]; }

#define LOADPX(DST, KCI) { \
    const float* xb = x + (KCI) * KC; \
    _Pragma("unroll") \
    for (int j = 0; j < 8; ++j) { \
        int li = t + j * 256; \
        DST[j] = *reinterpret_cast<const f32x4*>(xb + (li >> 6) * IN_D + (li & 63) * 4); } }

#define LOADSC(AM, CD, OF, GA, GC, KCI) { \
    int bidx = o * 64 + (KCI) * 4 + (wseg >> 1); \
    int gidx = o * 16 + (KCI); \
    AM = absmax[bidx]; CD = code[bidx]; OF = offset[bidx]; \
    GA = g_absmax[gidx]; GC = g_code[gidx]; }

#define BODY(PK, PX, AM, CD, OF, GA, GC, PKN, PXN, AMN, CDN, OFN, GAN, GCN, KCI) { \
    /* prefetch chunk KCI+1 (lands during dequant+barrier+MFMA) */ \
    if ((KCI) + 1 < CHUNKS) { \
        LOADPK(PKN, (KCI) + 1); \
        LOADPX(PXN, (KCI) + 1); \
        LOADSC(AMN, CDN, OFN, GAN, GCN, (KCI) + 1); \
    } \
    /* dequant W chunk -> wlds[p] */ \
    { \
        const float cs  = (AM / CD) * (GA / GC); \
        const float noc = -OF * cs; \
        u16* wdst = &wlds[p][wrow * LSTRIDE + wseg * 32]; \
        _Pragma("unroll") \
        for (int j = 0; j < 4; ++j) { \
            bf16x8 r; \
            _Pragma("unroll") \
            for (int wi = 0; wi < 4; ++wi) { \
                int w = PK[j][wi]; \
                r[wi * 2]     = (__bf16)fmaf((float)(w & 15),        cs, noc); \
                r[wi * 2 + 1] = (__bf16)fmaf((float)((w >> 4) & 15), cs, noc); \
            } \
            *reinterpret_cast<bf16x8*>(wdst + j * 8) = r; \
        } \
    } \
    /* cvt x chunk -> xlds[p] */ \
    { \
        _Pragma("unroll") \
        for (int j = 0; j < 8; ++j) { \
            int li = t + j * 256; \
            bf16x4 h; \
            h[0] = (__bf16)PX[j][0]; h[1] = (__bf16)PX[j][1]; \
            h[2] = (__bf16)PX[j][2]; h[3] = (__bf16)PX[j][3]; \
            *reinterpret_cast<bf16x4*>(&xlds[p][(li >> 6) * LSTRIDE + (li & 63) * 4]) = h; \
        } \
    } \
    __syncthreads(); \
    /* MFMA: wave's 16x16 tile, 8 k-steps of 32 */ \
    { \
        const u16* xp = &xlds[p][(m_base + frow) * LSTRIDE + kk]; \
        const u16* wp = &wlds[p][(n_base + frow) * LSTRIDE + kk]; \
        _Pragma("unroll") \
        for (int ks = 0; ks < KC / 32; ++ks) { \
            bf16x8 a = *reinterpret_cast<const bf16x8*>(xp + ks * 32); \
            bf16x8 b = *reinterpret_cast<const bf16x8*>(wp + ks * 32); \
            acc = __builtin_amdgcn_mfma_f32_16x16x32_bf16(a, b, acc, 0, 0, 0); \
        } \
    } \
    p ^= 1; }

    // prologue: load chunk 0 into set A
    LOADPK(pkA, 0);
    LOADPX(pxA, 0);
    LOADSC(amA, cdA, ofA, gaA, gcA, 0);

    int p = 0;
    for (int ic = 0; ic < CHUNKS; ic += 2) {
        BODY(pkA, pxA, amA, cdA, ofA, gaA, gcA,
             pkB, pxB, amB, cdB, ofB, gaB, gcB, ic);
        BODY(pkB, pxB, amB, cdB, ofB, gaB, gcB,
             pkA, pxA, amA, cdA, ofA, gaA, gcA, ic + 1);
    }

    // ---- epilogue: D col = lane&15 (out col), row = (lane>>4)*4 + i (batch) ----
    const int oc = o_base + n_base + frow;
    const int r0 = m_base + (lane >> 4) * 4;
    #pragma unroll
    for (int i = 0; i < 4; ++i) {
        out[(r0 + i) * OUT_D + oc] = acc[i];
    }
}

extern "C" void kernel_launch(void* const* d_in, const int* in_sizes, int n_in,
                              void* d_out, int out_size, void* d_ws, size_t ws_size,
                              hipStream_t stream) {
    const void* px = nullptr;
    const void* ppk = nullptr;
    const void* trio[3] = {nullptr, nullptr, nullptr};
    const void* pair[2] = {nullptr, nullptr};
    int ntrio = 0, npair = 0;
    const int SZ_X   = B_D * IN_D;            // 131072
    const int SZ_PK  = OUT_D * (IN_D / 2);    // 29360128
    const int SZ_NB  = OUT_D * (IN_D / 64);   // 917504
    const int SZ_NG  = OUT_D * (IN_D / 256);  // 229376
    for (int i = 0; i < n_in; ++i) {
        int s = in_sizes[i];
        if (s == SZ_X) px = d_in[i];
        else if (s == SZ_PK) ppk = d_in[i];
        else if (s == SZ_NB) { if (ntrio < 3) trio[ntrio++] = d_in[i]; }
        else if (s == SZ_NG) { if (npair < 2) pair[npair++] = d_in[i]; }
    }
    if (!px || !ppk || ntrio != 3 || npair != 2) {
        px = d_in[0]; ppk = d_in[1];
        trio[0] = d_in[2]; trio[1] = d_in[3]; trio[2] = d_in[4];
        pair[0] = d_in[5]; pair[1] = d_in[6];
    }

    nf4_linear_kernel<<<dim3(OUT_D / OTILE), dim3(256), 0, stream>>>(
        (const float*)px, (const int*)ppk,
        (const float*)trio[0], (const float*)trio[1], (const float*)trio[2],
        (const float*)pair[0], (const float*)pair[1],
        (float*)d_out);
}